// Round 1
// baseline (1843.681 us; speedup 1.0000x reference)
//
#include <hip/hip_runtime.h>

#define N_NODES 100000
#define N_EDGES 600000
#define D 128

// ws layout (floats): [Wt_intra: D*D][Wt_inter: D*D][intra_src: N_NODES*D]
// Wt_* are transposed weights: Wt[k*D+d] = W[d*D+k], so the GEMV inner loop
// reads consecutive d across lanes (coalesced, L1-resident 64KB matrix).

__global__ void transpose_w_kernel(const float* __restrict__ Wi,
                                   const float* __restrict__ We,
                                   float* __restrict__ Wti,
                                   float* __restrict__ Wte) {
    int i = blockIdx.x * blockDim.x + threadIdx.x;
    if (i < D * D) {
        int d = i / D, k = i % D;
        Wti[k * D + d] = Wi[i];
        Wte[k * D + d] = We[i];
    }
}

// One block (128 threads) per row; rows [0,N) -> intra_src = src_x @ W_intra^T,
// rows [N,2N) -> d_out = dst_x @ W_intra^T (pre-activation self_msg).
__global__ void node_transform_kernel(const float* __restrict__ src_x,
                                      const float* __restrict__ dst_x,
                                      const float* __restrict__ Wt,
                                      float* __restrict__ intra_src,
                                      float* __restrict__ out) {
    __shared__ float xs[D];
    int r = blockIdx.x;
    const float* x;
    float* o;
    if (r < N_NODES) {
        x = src_x + (size_t)r * D;
        o = intra_src + (size_t)r * D;
    } else {
        int rr = r - N_NODES;
        x = dst_x + (size_t)rr * D;
        o = out + (size_t)rr * D;
    }
    int d = threadIdx.x;
    xs[d] = x[d];
    __syncthreads();
    float acc = 0.0f;
    const float4* p4 = (const float4*)xs;
    for (int k4 = 0; k4 < D / 4; ++k4) {
        float4 pv = p4[k4];   // LDS broadcast (same address all lanes)
        int kb = k4 * 4;
        acc += pv.x * Wt[(kb + 0) * D + d];
        acc += pv.y * Wt[(kb + 1) * D + d];
        acc += pv.z * Wt[(kb + 2) * D + d];
        acc += pv.w * Wt[(kb + 3) * D + d];
    }
    o[d] = acc;
}

// One block (128 threads) per edge.
__global__ void edge_kernel(const float* __restrict__ src_x,
                            const float* __restrict__ dst_x,
                            const int* __restrict__ src_idx,
                            const int* __restrict__ dst_idx,
                            const float* __restrict__ ew,
                            const float* __restrict__ Wt,      // transposed W_inter
                            const float* __restrict__ intra_src,
                            float* __restrict__ out) {
    __shared__ float ps[D];
    int e = blockIdx.x;
    int s = src_idx[e];   // uniform -> scalar load
    int t = dst_idx[e];
    float w = ew[e];
    int d = threadIdx.x;
    ps[d] = src_x[(size_t)s * D + d] * dst_x[(size_t)t * D + d];
    __syncthreads();
    float m = 0.0f;
    const float4* p4 = (const float4*)ps;
    for (int k4 = 0; k4 < D / 4; ++k4) {
        float4 pv = p4[k4];   // LDS broadcast
        int kb = k4 * 4;
        m += pv.x * Wt[(kb + 0) * D + d];
        m += pv.y * Wt[(kb + 1) * D + d];
        m += pv.z * Wt[(kb + 2) * D + d];
        m += pv.w * Wt[(kb + 3) * D + d];
    }
    float msg = w * (intra_src[(size_t)s * D + d] + m);
    atomicAdd(&out[(size_t)t * D + d], msg);
}

__global__ void leaky_relu_kernel(float* __restrict__ out, int n) {
    int i = blockIdx.x * blockDim.x + threadIdx.x;
    if (i < n) {
        float v = out[i];
        out[i] = v > 0.0f ? v : 0.01f * v;
    }
}

extern "C" void kernel_launch(void* const* d_in, const int* in_sizes, int n_in,
                              void* d_out, int out_size, void* d_ws, size_t ws_size,
                              hipStream_t stream) {
    const float* src_x = (const float*)d_in[0];
    const float* dst_x = (const float*)d_in[1];
    const int*   eidx  = (const int*)d_in[2];     // [2, E] flat: src then dst
    const float* ew    = (const float*)d_in[3];   // [E, 1]
    const float* Wi    = (const float*)d_in[4];   // [D, D]
    const float* We    = (const float*)d_in[5];   // [D, D]
    float* out = (float*)d_out;

    float* ws    = (float*)d_ws;
    float* Wti   = ws;                 // D*D
    float* Wte   = ws + D * D;         // D*D
    float* intra = ws + 2 * D * D;     // N_NODES*D

    const int* src_idx = eidx;
    const int* dst_idx = eidx + N_EDGES;

    transpose_w_kernel<<<(D * D + 255) / 256, 256, 0, stream>>>(Wi, We, Wti, Wte);

    node_transform_kernel<<<2 * N_NODES, D, 0, stream>>>(src_x, dst_x, Wti, intra, out);

    edge_kernel<<<N_EDGES, D, 0, stream>>>(src_x, dst_x, src_idx, dst_idx, ew,
                                           Wte, intra, out);

    leaky_relu_kernel<<<(N_NODES * D + 255) / 256, 256, 0, stream>>>(out, N_NODES * D);
}